// Round 3
// baseline (106.181 us; speedup 1.0000x reference)
//
#include <hip/hip_runtime.h>

// MapLoss: fused masked-MSE + pos/neg split loss over (32, 512, 512) f32 maps.
//
// Hot path: for these inputs (gt ~ U[0,1)), n_pos ~ 0.35-0.4*N >> N/4, so
// k = min(3*n_pos, n_neg) == n_neg for every row -> hard-negative top-k ==
// "mean over all negatives"; n_pos > 0 always (no top-500 fallback). So the
// streaming pass only needs per-(sample,map) {pos_sum, neg_sum, n_pos}.
//
// Single fused kernel: 2048 blocks stream the maps (32 waves/CU for latency
// hiding); each block stores 6 partials, release-fences, and takes a ticket;
// the LAST block acquire-fences and finalizes entirely on-chip. Rare paths
// (k < n_neg or n_pos == 0; never exercised here) are exact via a cooperative
// shared-memory radix-select -- no per-thread arrays, so no scratch alloc.

#define NPS (512 * 512)          // elements per sample
#define BPS 64                   // blocks per sample
#define EPB 4096                 // elements per block: 256 thr * 4 iter * 4 f32
#define NB 32                    // batch
#define NBLK (BPS * NB)          // 2048 blocks

constexpr float THR_REGION = 0.6f;
constexpr float THR_AFF    = 0.65f;

// ---- cooperative exact top-k sum (rare paths only; block-uniform call) ----
// Returns (to thread 0) the sum of the k largest loss-map values of one row.
// Values are >= 0 so float bit order == value order. 4 count-histogram passes
// find the exact k-th value T; final pass sums values > T deterministically
// (fixed per-thread j-order + fixed-order tree reduce) and adds ties * T.
__device__ float coop_topk_sum(const float* __restrict__ gt,
                               const float* __restrict__ pd,
                               const float* __restrict__ mm,
                               float thr, int k, bool negOnly, int tid) {
  __shared__ unsigned hcnt[256];
  __shared__ unsigned s_prefix;
  __shared__ int s_want;
  if (tid == 0) { s_prefix = 0; s_want = k; }
  __syncthreads();
  for (int shift = 24; shift >= 0; shift -= 8) {
    hcnt[tid] = 0;
    __syncthreads();
    const unsigned pfx = s_prefix;
    for (int j = tid; j < NPS; j += 256) {
      const float g = gt[j];
      const bool pos = g > thr;
      if (negOnly && pos) continue;
      float p = pd[j];
      if (pos && p > 1.0f) p = 1.0f;
      const float d = p - g;
      const float vv = d * d * mm[j];
      const unsigned u = __float_as_uint(vv);
      if (shift < 24 && (u >> (shift + 8)) != (pfx >> (shift + 8))) continue;
      atomicAdd(&hcnt[(u >> shift) & 255u], 1u);   // int counts: deterministic
    }
    __syncthreads();
    if (tid == 0) {
      int want = s_want;
      int bin = 255;
      for (; bin > 0; --bin) {
        if ((int)hcnt[bin] < want) want -= (int)hcnt[bin];
        else break;
      }
      s_want = want;
      s_prefix |= ((unsigned)bin) << shift;
    }
    __syncthreads();
  }
  const unsigned T = s_prefix;   // bit pattern of k-th largest value
  const int ties = s_want;       // copies of T still needed
  float psum = 0.f;
  for (int j = tid; j < NPS; j += 256) {
    const float g = gt[j];
    const bool pos = g > thr;
    if (negOnly && pos) continue;
    float p = pd[j];
    if (pos && p > 1.0f) p = 1.0f;
    const float d = p - g;
    const float vv = d * d * mm[j];
    if (__float_as_uint(vv) > T) psum += vv;
  }
#pragma unroll
  for (int off = 32; off; off >>= 1) psum += __shfl_down(psum, off, 64);
  __shared__ float wsum[4];
  if ((tid & 63) == 0) wsum[tid >> 6] = psum;
  __syncthreads();
  float total = 0.f;
  if (tid == 0)
    total = ((wsum[0] + wsum[1]) + (wsum[2] + wsum[3])) +
            (float)ties * __uint_as_float(T);
  __syncthreads();               // shared arrays reused across rows
  return total;
}

// ---------------- fused kernel ----------------
// grid (BPS, NB) = 2048 blocks x 256 thr. part[b][blk][6] =
// {posSumR, negSumR, cntR, posSumA, negSumA, cntA}. No float atomics anywhere.
__global__ __launch_bounds__(256) void map_loss_fused(
    const float* __restrict__ rg, const float* __restrict__ ag,
    const float* __restrict__ rp, const float* __restrict__ ap,
    const float* __restrict__ mk,
    unsigned* __restrict__ counter, float* __restrict__ part,
    float* __restrict__ out) {
  const int b   = blockIdx.y;
  const int tid = threadIdx.x;
  const size_t sbase = (size_t)b * NPS + (size_t)blockIdx.x * EPB;

  float v[6] = {0.f, 0.f, 0.f, 0.f, 0.f, 0.f};  // posR negR cntR posA negA cntA

#pragma unroll
  for (int jj = 0; jj < 4; ++jj) {
    const size_t base = sbase + (size_t)jj * 1024 + (size_t)tid * 4;
    const float4 g_r = *reinterpret_cast<const float4*>(rg + base);
    const float4 g_a = *reinterpret_cast<const float4*>(ag + base);
    const float4 p_r = *reinterpret_cast<const float4*>(rp + base);
    const float4 p_a = *reinterpret_cast<const float4*>(ap + base);
    const float4 m_4 = *reinterpret_cast<const float4*>(mk + base);
    const float* gr = reinterpret_cast<const float*>(&g_r);
    const float* ga = reinterpret_cast<const float*>(&g_a);
    const float* pr = reinterpret_cast<const float*>(&p_r);
    const float* pa = reinterpret_cast<const float*>(&p_a);
    const float* mm = reinterpret_cast<const float*>(&m_4);
#pragma unroll
    for (int j = 0; j < 4; ++j) {
      const float m = mm[j];
      {  // region
        const float g = gr[j];
        float p = pr[j];
        const bool pos = g > THR_REGION;
        if (pos && p > 1.0f) p = 1.0f;
        const float d = p - g;
        const float l = d * d * m;
        if (pos) { v[0] += l; v[2] += 1.0f; } else { v[1] += l; }
      }
      {  // affinity
        const float g = ga[j];
        float p = pa[j];
        const bool pos = g > THR_AFF;
        if (pos && p > 1.0f) p = 1.0f;
        const float d = p - g;
        const float l = d * d * m;
        if (pos) { v[3] += l; v[5] += 1.0f; } else { v[4] += l; }
      }
    }
  }

  // wave64 shuffle reduce, then cross-wave via LDS
#pragma unroll
  for (int q = 0; q < 6; ++q)
#pragma unroll
    for (int off = 32; off > 0; off >>= 1)
      v[q] += __shfl_down(v[q], off, 64);

  __shared__ float shW[4][6];
  const int lane = tid & 63, wid = tid >> 6;
  if (lane == 0) {
#pragma unroll
    for (int q = 0; q < 6; ++q) shW[wid][q] = v[q];
  }
  __syncthreads();

  // tid0-only store + release fence + ticket (single-thread release chain)
  __shared__ int islast;
  if (tid == 0) {
    float* dst = part + ((size_t)b * BPS + blockIdx.x) * 6;
#pragma unroll
    for (int q = 0; q < 6; ++q)
      dst[q] = shW[0][q] + shW[1][q] + shW[2][q] + shW[3][q];
    __threadfence();                       // release: partials -> visible
    const unsigned tk = atomicAdd(counter, 1u);
    islast = (tk == NBLK - 1) ? 1 : 0;
  }
  __syncthreads();
  if (!islast) return;

  // ---------------- finalize (last block only) ----------------
  __threadfence();                         // acquire: see all partials

  __shared__ float rsum[64][3];
  {
    const int row = tid >> 2, sub = tid & 3;
    const int mapA = row >> 5, bb = row & 31;
    float ps = 0.f, ns = 0.f, cf = 0.f;
    for (int blk = sub; blk < BPS; blk += 4) {
      const float* p = part + ((size_t)bb * BPS + blk) * 6 + mapA * 3;
      ps += p[0]; ns += p[1]; cf += p[2];
    }
#pragma unroll
    for (int m2 = 1; m2 <= 2; m2 <<= 1) {
      ps += __shfl_xor(ps, m2, 64);
      ns += __shfl_xor(ns, m2, 64);
      cf += __shfl_xor(cf, m2, 64);
    }
    if (sub == 0) { rsum[row][0] = ps; rsum[row][1] = ns; rsum[row][2] = cf; }
  }
  __syncthreads();

  __shared__ float per[64];
  __shared__ int needK[64];   // 0 = hot path done; >0 = top-k(neg); -1 = top500
  if (tid < 64) {
    const int row = tid;
    const int npos = (int)rsum[row][2];    // counts are exact integers
    const int nneg = NPS - npos;
    long long k = 3LL * npos;
    if (k > nneg) k = nneg;
    float p_s = 0.f;
    int nk = 0;
    if (npos > 0) {
      const float pos_loss = rsum[row][0] / (float)npos;
      float neg_loss = 0.f;
      if (k > 0) {
        if (k == (long long)nneg) neg_loss = rsum[row][1] / (float)nneg;  // hot
        else nk = (int)k;                                                 // rare
      }
      p_s = pos_loss + neg_loss;
    } else {
      nk = -1;                                                            // rare
    }
    per[row] = p_s;
    needK[row] = nk;
  }
  __syncthreads();

  // rare rows: block-uniform loop (needK in shared), cooperative radix-select
  for (int row = 0; row < 64; ++row) {
    const int nk = needK[row];
    if (nk == 0) continue;
    const int mapA = row >> 5, bb = row & 31;
    const float thr = mapA ? THR_AFF : THR_REGION;
    const float* gt = (mapA ? ag : rg) + (size_t)bb * NPS;
    const float* pd = (mapA ? ap : rp) + (size_t)bb * NPS;
    const float* mm = mk + (size_t)bb * NPS;
    const bool negOnly = (nk > 0);
    const int k = negOnly ? nk : 500;
    const float tsum = coop_topk_sum(gt, pd, mm, thr, k, negOnly, tid);
    if (tid == 0) per[row] += tsum / (float)k;
    __syncthreads();
  }

  if (tid == 0) {
    float cs = 0.f, as_ = 0.f;
    for (int i = 0; i < 32; ++i) { cs += per[i]; as_ += per[32 + i]; }
    out[0] = 2.0f * cs / (float)NB + as_ / (float)NB;
  }
}

extern "C" void kernel_launch(void* const* d_in, const int* in_sizes, int n_in,
                              void* d_out, int out_size, void* d_ws, size_t ws_size,
                              hipStream_t stream) {
  const float* rg = (const float*)d_in[0];
  const float* ag = (const float*)d_in[1];
  const float* rp = (const float*)d_in[2];
  const float* ap = (const float*)d_in[3];
  const float* mk = (const float*)d_in[4];
  float* out = (float*)d_out;

  unsigned* counter = (unsigned*)d_ws;                       // 1 u32, zeroed per call
  float* part = (float*)((char*)d_ws + 64);                  // [NB][BPS][6] = 48 KB

  hipMemsetAsync(counter, 0, sizeof(unsigned), stream);      // graph-capturable
  dim3 grid(BPS, NB);
  map_loss_fused<<<grid, 256, 0, stream>>>(rg, ag, rp, ap, mk, counter, part, out);
}

// Round 4
// 35.306 us; speedup vs baseline: 3.0074x; 3.0074x over previous
//
#include <hip/hip_runtime.h>

// MapLoss: fused masked-MSE + pos/neg split loss over (32, 512, 512) f32 maps.
//
// Hot path: for these inputs (gt ~ U[0,1)), n_pos ~ 0.35-0.4*N >> N/4, so
// k = min(3*n_pos, n_neg) == n_neg for every row -> hard-negative top-k ==
// "mean over all negatives"; n_pos > 0 always (no top-500 fallback). The
// streaming pass only needs per-(sample,map) {pos_sum, neg_sum, n_pos}.
//
// R3 lesson: single-kernel last-block reduction regressed 3x -- the per-block
// device-scope __threadfence (L2 writeback) serialized the stream. Two kernels;
// the kernel boundary is the sync.
//
// R4 lever: pass1 was latency-bound at VGPR=32 (~2-4 loads in flight/wave,
// ~23% of HBM). Each thread now issues ALL 20 float4 loads back-to-back into
// registers (load-all-then-compute), trading occupancy (8->5 waves/SIMD) for
// ~3x in-flight bytes per CU.

#define NPS (512 * 512)          // elements per sample
#define BPS 64                   // blocks per sample (pass1)
#define EPB 4096                 // elements per block: 256 thr * 4 float4
#define NB 32                    // batch

constexpr float THR_REGION = 0.6f;
constexpr float THR_AFF    = 0.65f;

// ---------------- pass 1: streaming fused accumulate ----------------
// grid (BPS, NB) = 2048 blocks x 256 thr. part[b][blk][6] =
// {posSumR, negSumR, cntR, posSumA, negSumA, cntA}. No atomics: deterministic.
__global__ __launch_bounds__(256) void map_loss_pass1(
    const float* __restrict__ rg, const float* __restrict__ ag,
    const float* __restrict__ rp, const float* __restrict__ ap,
    const float* __restrict__ mk, float* __restrict__ part) {
  const int b   = blockIdx.y;
  const int tid = threadIdx.x;
  const size_t sbase = (size_t)b * NPS + (size_t)blockIdx.x * EPB + (size_t)tid * 4;

  const float4* Gr = reinterpret_cast<const float4*>(rg + sbase);
  const float4* Ga = reinterpret_cast<const float4*>(ag + sbase);
  const float4* Pr = reinterpret_cast<const float4*>(rp + sbase);
  const float4* Pa = reinterpret_cast<const float4*>(ap + sbase);
  const float4* Mm = reinterpret_cast<const float4*>(mk + sbase);

  // ---- issue all 20 loads, then compute (maximize outstanding VMEM) ----
  float4 vg[4], va[4], vp[4], vq[4], vm[4];
#pragma unroll
  for (int jj = 0; jj < 4; ++jj) {
    vg[jj] = Gr[jj * 256];   // stride 1024 floats between jj slabs
    va[jj] = Ga[jj * 256];
    vp[jj] = Pr[jj * 256];
    vq[jj] = Pa[jj * 256];
    vm[jj] = Mm[jj * 256];
  }

  float v[6] = {0.f, 0.f, 0.f, 0.f, 0.f, 0.f};  // posR negR cntR posA negA cntA
#pragma unroll
  for (int jj = 0; jj < 4; ++jj) {
    const float* gr = reinterpret_cast<const float*>(&vg[jj]);
    const float* ga = reinterpret_cast<const float*>(&va[jj]);
    const float* pr = reinterpret_cast<const float*>(&vp[jj]);
    const float* pa = reinterpret_cast<const float*>(&vq[jj]);
    const float* mm = reinterpret_cast<const float*>(&vm[jj]);
#pragma unroll
    for (int j = 0; j < 4; ++j) {
      const float m = mm[j];
      {  // region
        const float g = gr[j];
        float p = pr[j];
        const bool pos = g > THR_REGION;
        if (pos && p > 1.0f) p = 1.0f;
        const float d = p - g;
        const float l = d * d * m;
        if (pos) { v[0] += l; v[2] += 1.0f; } else { v[1] += l; }
      }
      {  // affinity
        const float g = ga[j];
        float p = pa[j];
        const bool pos = g > THR_AFF;
        if (pos && p > 1.0f) p = 1.0f;
        const float d = p - g;
        const float l = d * d * m;
        if (pos) { v[3] += l; v[5] += 1.0f; } else { v[4] += l; }
      }
    }
  }

  // wave64 shuffle reduce, then cross-wave via LDS
#pragma unroll
  for (int q = 0; q < 6; ++q)
#pragma unroll
    for (int off = 32; off > 0; off >>= 1)
      v[q] += __shfl_down(v[q], off, 64);

  __shared__ float sh[4][6];
  const int lane = tid & 63, wid = tid >> 6;
  if (lane == 0) {
#pragma unroll
    for (int q = 0; q < 6; ++q) sh[wid][q] = v[q];
  }
  __syncthreads();
  if (tid < 6) {
    const float s = sh[0][tid] + sh[1][tid] + sh[2][tid] + sh[3][tid];
    part[((size_t)b * BPS + blockIdx.x) * 6 + tid] = s;
  }
}

// ---------------- exact serial radix-select (rare paths only) ----------------
// Sum of top-k of the per-element loss map for one (sample,map) row. Values are
// >= 0 so float bit order == value order. 4 passes of 256-bin byte histograms.
__device__ float topk_sum_row(const float* __restrict__ gt,
                              const float* __restrict__ pd,
                              const float* __restrict__ mm,
                              float thr, int k, bool negOnly) {
  unsigned prefix = 0;
  float sum_def = 0.f;
  int want = k;
  for (int shift = 24; shift >= 0; shift -= 8) {
    unsigned cnt[256];
    float bsum[256];
    for (int i = 0; i < 256; ++i) { cnt[i] = 0; bsum[i] = 0.f; }
    for (int j = 0; j < NPS; ++j) {
      const float g = gt[j];
      const bool pos = g > thr;
      if (negOnly && pos) continue;
      float p = pd[j];
      if (pos && p > 1.0f) p = 1.0f;
      const float d = p - g;
      const float vv = d * d * mm[j];
      const unsigned u = __float_as_uint(vv);
      if (shift < 24 && (u >> (shift + 8)) != (prefix >> (shift + 8))) continue;
      const unsigned bin = (u >> shift) & 255u;
      cnt[bin]++;
      bsum[bin] += vv;
    }
    int bin = 255;
    for (; bin > 0; --bin) {
      if ((int)cnt[bin] < want) { want -= (int)cnt[bin]; sum_def += bsum[bin]; }
      else break;
    }
    prefix |= ((unsigned)bin) << shift;
  }
  sum_def += (float)want * __uint_as_float(prefix);
  return sum_def;
}

// ---------------- pass 2: parallel finalize ----------------
// 1 block x 256 threads. Row r = (map,sample) handled by 4 lanes; each lane
// sums 16 of the 64 partial-triples, then 2 shfl_xor steps combine the group.
__global__ __launch_bounds__(256) void map_loss_pass2(
    const float* __restrict__ part,
    const float* __restrict__ rg, const float* __restrict__ ag,
    const float* __restrict__ rp, const float* __restrict__ ap,
    const float* __restrict__ mk, float* __restrict__ out) {
  const int t = threadIdx.x;
  const int row = t >> 2;        // 0..63
  const int sub = t & 3;
  const int mapA = row >> 5;     // 0 = region, 1 = affinity
  const int b = row & 31;

  float posSum = 0.f, negSum = 0.f, cntF = 0.f;
  for (int blk = sub; blk < BPS; blk += 4) {
    const float* p = part + ((size_t)b * BPS + blk) * 6 + mapA * 3;
    posSum += p[0];
    negSum += p[1];
    cntF   += p[2];
  }
#pragma unroll
  for (int msk = 1; msk <= 2; msk <<= 1) {
    posSum += __shfl_xor(posSum, msk, 64);
    negSum += __shfl_xor(negSum, msk, 64);
    cntF   += __shfl_xor(cntF, msk, 64);
  }

  __shared__ float sh[64];
  if (sub == 0) {
    const int npos = (int)cntF;           // partial counts are exact integers
    const int nneg = NPS - npos;
    long long k = 3LL * npos;
    if (k > nneg) k = nneg;

    const float thr = mapA ? THR_AFF : THR_REGION;
    const float* gt = (mapA ? ag : rg) + (size_t)b * NPS;
    const float* pd = (mapA ? ap : rp) + (size_t)b * NPS;
    const float* mm = mk + (size_t)b * NPS;

    float per_sample;
    if (npos > 0) {
      const float pos_loss = posSum / (float)npos;
      float neg_loss = 0.f;
      if (k > 0) {
        if (k == (long long)nneg) {
          neg_loss = negSum / (float)nneg;             // hot path
        } else {
          neg_loss = topk_sum_row(gt, pd, mm, thr, (int)k, true) / (float)k;
        }
      }
      per_sample = pos_loss + neg_loss;
    } else {
      per_sample = topk_sum_row(gt, pd, mm, thr, 500, false) / 500.0f;
    }
    sh[row] = per_sample;
  }
  __syncthreads();
  if (t == 0) {
    float char_sum = 0.f, affi_sum = 0.f;
    for (int i = 0; i < 32; ++i) { char_sum += sh[i]; affi_sum += sh[32 + i]; }
    out[0] = 2.0f * char_sum / (float)NB + affi_sum / (float)NB;
  }
}

extern "C" void kernel_launch(void* const* d_in, const int* in_sizes, int n_in,
                              void* d_out, int out_size, void* d_ws, size_t ws_size,
                              hipStream_t stream) {
  const float* rg = (const float*)d_in[0];
  const float* ag = (const float*)d_in[1];
  const float* rp = (const float*)d_in[2];
  const float* ap = (const float*)d_in[3];
  const float* mk = (const float*)d_in[4];
  float* out = (float*)d_out;
  float* part = (float*)d_ws;  // [NB][BPS][6] f32 = 48 KB, fully rewritten per call

  dim3 grid1(BPS, NB);
  map_loss_pass1<<<grid1, 256, 0, stream>>>(rg, ag, rp, ap, mk, part);
  map_loss_pass2<<<1, 256, 0, stream>>>(part, rg, ag, rp, ap, mk, out);
}

// Round 5
// 35.172 us; speedup vs baseline: 3.0189x; 1.0038x over previous
//
#include <hip/hip_runtime.h>

// MapLoss: fused masked-MSE + pos/neg split loss over (32, 512, 512) f32 maps.
//
// Hot path: for these inputs (gt ~ U[0,1)), n_pos ~ 0.35-0.4*N >> N/4, so
// k = min(3*n_pos, n_neg) == n_neg for every row -> hard-negative top-k ==
// "mean over all negatives"; n_pos > 0 always (no top-500 fallback). The
// streaming pass only needs per-(sample,map) {pos_sum, neg_sum, n_pos}.
//
// R3 lesson: single-kernel last-block reduction regressed 3x (per-block
// device fence serializes the stream). Two kernels; boundary is the sync.
// R4 lesson: source-level load-all-then-compute is DEFEATED by the scheduler
// (VGPR stayed 36 -> ~4 loads in flight -> ~5 TB/s effective). R5 pins the
// 20-load cluster with __builtin_amdgcn_sched_barrier(0): compute cannot be
// hoisted above it, so all 20 float4 stay live (~80 data VGPRs, 3-5x
// in-flight bytes per CU on a latency-bound stream).

#define NPS (512 * 512)          // elements per sample
#define BPS 64                   // blocks per sample (pass1)
#define EPB 4096                 // elements per block: 256 thr * 4 float4
#define NB 32                    // batch

constexpr float THR_REGION = 0.6f;
constexpr float THR_AFF    = 0.65f;

// ---------------- pass 1: streaming fused accumulate ----------------
// grid (BPS, NB) = 2048 blocks x 256 thr. part[b][blk][6] =
// {posSumR, negSumR, cntR, posSumA, negSumA, cntA}. No atomics: deterministic.
__global__ __launch_bounds__(256) void map_loss_pass1(
    const float* __restrict__ rg, const float* __restrict__ ag,
    const float* __restrict__ rp, const float* __restrict__ ap,
    const float* __restrict__ mk, float* __restrict__ part) {
  const int b   = blockIdx.y;
  const int tid = threadIdx.x;
  const size_t sbase = (size_t)b * NPS + (size_t)blockIdx.x * EPB + (size_t)tid * 4;

  const float4* Gr = reinterpret_cast<const float4*>(rg + sbase);
  const float4* Ga = reinterpret_cast<const float4*>(ag + sbase);
  const float4* Pr = reinterpret_cast<const float4*>(rp + sbase);
  const float4* Pa = reinterpret_cast<const float4*>(ap + sbase);
  const float4* Mm = reinterpret_cast<const float4*>(mk + sbase);

  // ---- issue all 20 loads; sched_barrier(0) makes them un-sinkable ----
  float4 vg[4], va[4], vp[4], vq[4], vm[4];
#pragma unroll
  for (int jj = 0; jj < 4; ++jj) {
    vg[jj] = Gr[jj * 256];   // stride 1024 floats between jj slabs
    va[jj] = Ga[jj * 256];
    vp[jj] = Pr[jj * 256];
    vq[jj] = Pa[jj * 256];
    vm[jj] = Mm[jj * 256];
  }
  __builtin_amdgcn_sched_barrier(0);   // nothing crosses: 20 loads in flight

  float v[6] = {0.f, 0.f, 0.f, 0.f, 0.f, 0.f};  // posR negR cntR posA negA cntA
#pragma unroll
  for (int jj = 0; jj < 4; ++jj) {
    const float* gr = reinterpret_cast<const float*>(&vg[jj]);
    const float* ga = reinterpret_cast<const float*>(&va[jj]);
    const float* pr = reinterpret_cast<const float*>(&vp[jj]);
    const float* pa = reinterpret_cast<const float*>(&vq[jj]);
    const float* mm = reinterpret_cast<const float*>(&vm[jj]);
#pragma unroll
    for (int j = 0; j < 4; ++j) {
      const float m = mm[j];
      {  // region
        const float g = gr[j];
        float p = pr[j];
        const bool pos = g > THR_REGION;
        if (pos && p > 1.0f) p = 1.0f;
        const float d = p - g;
        const float l = d * d * m;
        if (pos) { v[0] += l; v[2] += 1.0f; } else { v[1] += l; }
      }
      {  // affinity
        const float g = ga[j];
        float p = pa[j];
        const bool pos = g > THR_AFF;
        if (pos && p > 1.0f) p = 1.0f;
        const float d = p - g;
        const float l = d * d * m;
        if (pos) { v[3] += l; v[5] += 1.0f; } else { v[4] += l; }
      }
    }
  }

  // wave64 shuffle reduce, then cross-wave via LDS
#pragma unroll
  for (int q = 0; q < 6; ++q)
#pragma unroll
    for (int off = 32; off > 0; off >>= 1)
      v[q] += __shfl_down(v[q], off, 64);

  __shared__ float sh[4][6];
  const int lane = tid & 63, wid = tid >> 6;
  if (lane == 0) {
#pragma unroll
    for (int q = 0; q < 6; ++q) sh[wid][q] = v[q];
  }
  __syncthreads();
  if (tid < 6) {
    const float s = sh[0][tid] + sh[1][tid] + sh[2][tid] + sh[3][tid];
    part[((size_t)b * BPS + blockIdx.x) * 6 + tid] = s;
  }
}

// ---------------- exact serial radix-select (rare paths only) ----------------
// Sum of top-k of the per-element loss map for one (sample,map) row. Values are
// >= 0 so float bit order == value order. 4 passes of 256-bin byte histograms.
__device__ float topk_sum_row(const float* __restrict__ gt,
                              const float* __restrict__ pd,
                              const float* __restrict__ mm,
                              float thr, int k, bool negOnly) {
  unsigned prefix = 0;
  float sum_def = 0.f;
  int want = k;
  for (int shift = 24; shift >= 0; shift -= 8) {
    unsigned cnt[256];
    float bsum[256];
    for (int i = 0; i < 256; ++i) { cnt[i] = 0; bsum[i] = 0.f; }
    for (int j = 0; j < NPS; ++j) {
      const float g = gt[j];
      const bool pos = g > thr;
      if (negOnly && pos) continue;
      float p = pd[j];
      if (pos && p > 1.0f) p = 1.0f;
      const float d = p - g;
      const float vv = d * d * mm[j];
      const unsigned u = __float_as_uint(vv);
      if (shift < 24 && (u >> (shift + 8)) != (prefix >> (shift + 8))) continue;
      const unsigned bin = (u >> shift) & 255u;
      cnt[bin]++;
      bsum[bin] += vv;
    }
    int bin = 255;
    for (; bin > 0; --bin) {
      if ((int)cnt[bin] < want) { want -= (int)cnt[bin]; sum_def += bsum[bin]; }
      else break;
    }
    prefix |= ((unsigned)bin) << shift;
  }
  sum_def += (float)want * __uint_as_float(prefix);
  return sum_def;
}

// ---------------- pass 2: parallel finalize ----------------
// 1 block x 256 threads. Row r = (map,sample) handled by 4 lanes; each lane
// sums 16 of the 64 partial-triples, then 2 shfl_xor steps combine the group.
__global__ __launch_bounds__(256) void map_loss_pass2(
    const float* __restrict__ part,
    const float* __restrict__ rg, const float* __restrict__ ag,
    const float* __restrict__ rp, const float* __restrict__ ap,
    const float* __restrict__ mk, float* __restrict__ out) {
  const int t = threadIdx.x;
  const int row = t >> 2;        // 0..63
  const int sub = t & 3;
  const int mapA = row >> 5;     // 0 = region, 1 = affinity
  const int b = row & 31;

  float posSum = 0.f, negSum = 0.f, cntF = 0.f;
  for (int blk = sub; blk < BPS; blk += 4) {
    const float* p = part + ((size_t)b * BPS + blk) * 6 + mapA * 3;
    posSum += p[0];
    negSum += p[1];
    cntF   += p[2];
  }
#pragma unroll
  for (int msk = 1; msk <= 2; msk <<= 1) {
    posSum += __shfl_xor(posSum, msk, 64);
    negSum += __shfl_xor(negSum, msk, 64);
    cntF   += __shfl_xor(cntF, msk, 64);
  }

  __shared__ float sh[64];
  if (sub == 0) {
    const int npos = (int)cntF;           // partial counts are exact integers
    const int nneg = NPS - npos;
    long long k = 3LL * npos;
    if (k > nneg) k = nneg;

    const float thr = mapA ? THR_AFF : THR_REGION;
    const float* gt = (mapA ? ag : rg) + (size_t)b * NPS;
    const float* pd = (mapA ? ap : rp) + (size_t)b * NPS;
    const float* mm = mk + (size_t)b * NPS;

    float per_sample;
    if (npos > 0) {
      const float pos_loss = posSum / (float)npos;
      float neg_loss = 0.f;
      if (k > 0) {
        if (k == (long long)nneg) {
          neg_loss = negSum / (float)nneg;             // hot path
        } else {
          neg_loss = topk_sum_row(gt, pd, mm, thr, (int)k, true) / (float)k;
        }
      }
      per_sample = pos_loss + neg_loss;
    } else {
      per_sample = topk_sum_row(gt, pd, mm, thr, 500, false) / 500.0f;
    }
    sh[row] = per_sample;
  }
  __syncthreads();
  if (t == 0) {
    float char_sum = 0.f, affi_sum = 0.f;
    for (int i = 0; i < 32; ++i) { char_sum += sh[i]; affi_sum += sh[32 + i]; }
    out[0] = 2.0f * char_sum / (float)NB + affi_sum / (float)NB;
  }
}

extern "C" void kernel_launch(void* const* d_in, const int* in_sizes, int n_in,
                              void* d_out, int out_size, void* d_ws, size_t ws_size,
                              hipStream_t stream) {
  const float* rg = (const float*)d_in[0];
  const float* ag = (const float*)d_in[1];
  const float* rp = (const float*)d_in[2];
  const float* ap = (const float*)d_in[3];
  const float* mk = (const float*)d_in[4];
  float* out = (float*)d_out;
  float* part = (float*)d_ws;  // [NB][BPS][6] f32 = 48 KB, fully rewritten per call

  dim3 grid1(BPS, NB);
  map_loss_pass1<<<grid1, 256, 0, stream>>>(rg, ag, rp, ap, mk, part);
  map_loss_pass2<<<1, 256, 0, stream>>>(part, rg, ag, rp, ap, mk, out);
}